// Round 16
// baseline (318.799 us; speedup 1.0000x reference)
//
#include <hip/hip_runtime.h>
#include <math.h>

#define DIMX 1024
#define QKD  128
#define HIDD 2048
#define BATCH 4
#define SEQ  2048

typedef __bf16 bf16;
typedef __bf16 bf16x8 __attribute__((ext_vector_type(8)));
typedef __bf16 bf16x4v __attribute__((ext_vector_type(4)));
typedef float f32x4 __attribute__((ext_vector_type(4)));

__device__ __forceinline__ float siluf(float v) { return v / (1.f + expf(-v)); }
__device__ __forceinline__ void splitf(float x, bf16& h, bf16& l) {
    h = (bf16)x;
    l = (bf16)(x - (float)h);
}
__device__ __forceinline__ f32x4 mfma16(bf16x8 a, bf16x8 b, f32x4 c) {
    return __builtin_amdgcn_mfma_f32_16x16x32_bf16(a, b, c, 0, 0, 0);
}

typedef __attribute__((address_space(1))) const void cg_void;
typedef __attribute__((address_space(3))) void lds_void_t;
__device__ __forceinline__ void gload16(const bf16* g, bf16* l) {
    __builtin_amdgcn_global_load_lds((cg_void*)g, (lds_void_t*)l, 16, 0, 0);
}

template<int N> __device__ __forceinline__ void wait_vm() {
    if constexpr (N == 0)  asm volatile("s_waitcnt vmcnt(0)" ::: "memory");
    if constexpr (N == 3)  asm volatile("s_waitcnt vmcnt(3)" ::: "memory");
    if constexpr (N == 4)  asm volatile("s_waitcnt vmcnt(4)" ::: "memory");
    if constexpr (N == 6)  asm volatile("s_waitcnt vmcnt(6)" ::: "memory");
    if constexpr (N == 8)  asm volatile("s_waitcnt vmcnt(8)" ::: "memory");
}

#define SB0 __builtin_amdgcn_sched_barrier(0)

// -------------------- LayerNorm -> split bf16 hi/lo --------------------
__global__ __launch_bounds__(256) void ln_split(const float* __restrict__ x,
                                                const float* __restrict__ scale,
                                                const float* __restrict__ bias,
                                                bf16* __restrict__ xh,
                                                bf16* __restrict__ xl) {
    const int row = blockIdx.x;
    const float4 v = reinterpret_cast<const float4*>(x + (size_t)row * DIMX)[threadIdx.x];
    float s  = v.x + v.y + v.z + v.w;
    float ss = v.x * v.x + v.y * v.y + v.z * v.z + v.w * v.w;
    #pragma unroll
    for (int off = 32; off; off >>= 1) {
        s  += __shfl_down(s, off);
        ss += __shfl_down(ss, off);
    }
    __shared__ float ls[4], lss[4];
    const int wid = threadIdx.x >> 6, lane = threadIdx.x & 63;
    if (lane == 0) { ls[wid] = s; lss[wid] = ss; }
    __syncthreads();
    if (threadIdx.x == 0) {
        float a = ls[0] + ls[1] + ls[2] + ls[3];
        float b = lss[0] + lss[1] + lss[2] + lss[3];
        float mu  = a / DIMX;
        float var = b / DIMX - mu * mu;
        ls[0]  = mu;
        lss[0] = rsqrtf(var + 1e-5f);
    }
    __syncthreads();
    const float mu = ls[0], rs = lss[0];
    const float4 sc = reinterpret_cast<const float4*>(scale)[threadIdx.x];
    const float4 bi = reinterpret_cast<const float4*>(bias)[threadIdx.x];
    float o[4];
    o[0] = (v.x - mu) * rs * sc.x + bi.x;
    o[1] = (v.y - mu) * rs * sc.y + bi.y;
    o[2] = (v.z - mu) * rs * sc.z + bi.z;
    o[3] = (v.w - mu) * rs * sc.w + bi.w;
    bf16x4v h, l;
    #pragma unroll
    for (int i = 0; i < 4; ++i) { bf16 hh, ll; splitf(o[i], hh, ll); h[i] = hh; l[i] = ll; }
    *reinterpret_cast<bf16x4v*>(xh + (size_t)row * DIMX + threadIdx.x * 4) = h;
    *reinterpret_cast<bf16x4v*>(xl + (size_t)row * DIMX + threadIdx.x * 4) = l;
}

// ------------- transpose + split: W [K][N] fp32 -> T[N][K] bf16 hi(/lo) -------------
__global__ __launch_bounds__(256) void wsplitT(const float* __restrict__ W, int K, int N,
                                               bf16* __restrict__ Th, bf16* __restrict__ Tl) {
    __shared__ float tile[32][33];
    const int bx = blockIdx.x * 32;   // N dir
    const int by = blockIdx.y * 32;   // K dir
    const int tx = threadIdx.x & 31, ty = threadIdx.x >> 5;
    #pragma unroll
    for (int r = 0; r < 32; r += 8)
        tile[ty + r][tx] = W[(size_t)(by + ty + r) * N + bx + tx];
    __syncthreads();
    #pragma unroll
    for (int r = 0; r < 32; r += 8) {
        const float v = tile[tx][ty + r];
        bf16 h, l; splitf(v, h, l);
        Th[(size_t)(bx + ty + r) * K + by + tx] = h;
        if (Tl) Tl[(size_t)(bx + ty + r) * K + by + tx] = l;
    }
}

// -------------------- add + bias: out = p0 + p1 + b[col] --------------------
__global__ __launch_bounds__(256) void addbias(const float* __restrict__ p0,
                                               const float* __restrict__ p1,
                                               const float* __restrict__ b,
                                               float* __restrict__ out,
                                               int total4) {   // total elems / 4
    for (int i = blockIdx.x * 256 + threadIdx.x; i < total4; i += gridDim.x * 256) {
        const float4 a = reinterpret_cast<const float4*>(p0)[i];
        const float4 c = reinterpret_cast<const float4*>(p1)[i];
        const int col = (i & (DIMX / 4 - 1)) * 4;
        float4 r;
        r.x = a.x + c.x + b[col + 0];
        r.y = a.y + c.y + b[col + 1];
        r.z = a.z + c.z + b[col + 2];
        r.w = a.w + c.w + b[col + 3];
        reinterpret_cast<float4*>(out)[i] = r;
    }
}

// =====================================================================
// gmm2: ring-buffered MFMA GEMM (round-9 proven, single-barrier loop).
// BM=256, BK=32, 512 threads (8 waves 2Mx4N), 4-deep LDS ring.
// Loop: [wait_vm(2L|L|0); barrier; ds_read(t); lgkm0; stage(t+3); MFMA(t)].
// WAR: stage(t+3) overwrites buf[(t-1)&3]; all iter-(t-1) reads completed
// before any wave passed barrier t.  RAW: wait_vm(2L) retires tile t.
// Epilogues (ALL natural row-major stores):
// EPI 5 (hid vT half, FLIPPED): rows=n; O[n][m]=silu(acc+e0[row])
// EPI 6 (hid gate half):        rows=m; O[m][n']=silu(acc+e0[n'])
// EPI 3 (av):   y[m][n] = acc * G[m][n]  bf16
// EPI 4 (out):  F[m][n] = acc + e0[n]  fp32
// =====================================================================
template<int EPI, int BN>
__global__ __launch_bounds__(512) void gmm2(
    const bf16* __restrict__ A, int lda, long long sA,
    const bf16* __restrict__ B, int ldb, long long sB,
    bf16* __restrict__ O, int ldo, long long sO,
    bf16* __restrict__ G, int ldg, long long sG,
    float* __restrict__ F, int ldf,
    const float* __restrict__ e0,
    int K) {

    constexpr int BM = 256, BK = 32;
    constexpr int AE = BM * BK;
    constexpr int BE = BN * BK;
    constexpr int CHA = AE / (512 * 8);
    constexpr int CHB = BE / (512 * 8);
    constexpr int L = CHA + CHB;
    constexpr int WN = BN / 4;
    constexpr int MI = 8, NI = WN / 16;

    __shared__ __align__(16) bf16 lds[4 * (AE + BE)];

    const int z = blockIdx.z;
    A += (size_t)sA * z;
    B += (size_t)sB * z;
    bf16* Oz = O ? O + (size_t)sO * z : nullptr;
    bf16* Gz = G ? G + (size_t)sG * z : nullptr;

    const int tid = threadIdx.x;
    const int l = tid & 63, w = tid >> 6;
    const int wr = w >> 2, wc = w & 3;
    const int lr = l & 15, ls4 = l >> 4;
    const int bm = blockIdx.y * BM, bn = blockIdx.x * BN;

    const bf16* aptr[CHA];
    #pragma unroll
    for (int c = 0; c < CHA; ++c) {
        const int flat = c * 512 + tid;
        const int row = flat >> 2;
        const int slot = (flat & 3) ^ ((row >> 1) & 3);
        aptr[c] = A + (size_t)(bm + row) * lda + slot * 8;
    }
    const bf16* bptr[CHB];
    #pragma unroll
    for (int c = 0; c < CHB; ++c) {
        const int flat = c * 512 + tid;
        const int row = flat >> 2;
        const int slot = (flat & 3) ^ ((row >> 1) & 3);
        bptr[c] = B + (size_t)(bn + row) * ldb + slot * 8;
    }

    int aoff[MI], boff[NI];
    #pragma unroll
    for (int i = 0; i < MI; ++i) {
        const int row = wr * 128 + i * 16 + lr;
        aoff[i] = row * BK + (ls4 ^ ((row >> 1) & 3)) * 8;
    }
    #pragma unroll
    for (int j = 0; j < NI; ++j) {
        const int row = wc * WN + j * 16 + lr;
        boff[j] = row * BK + (ls4 ^ ((row >> 1) & 3)) * 8;
    }

    const int NT = K / BK;
    f32x4 acc[MI][NI] = {};

    auto stage = [&](int tile) {
        const int buf = tile & 3;
        bf16* ab = lds + buf * (AE + BE);
        bf16* bb = ab + AE;
        #pragma unroll
        for (int c = 0; c < CHA; ++c)
            gload16(aptr[c] + tile * BK, ab + (c * 512 + w * 64) * 8);
        #pragma unroll
        for (int c = 0; c < CHB; ++c)
            gload16(bptr[c] + tile * BK, bb + (c * 512 + w * 64) * 8);
    };

    stage(0); SB0;
    stage(1); SB0;
    stage(2); SB0;

    for (int t = 0; t < NT; ++t) {
        const int ahead = NT - 1 - t;
        if (ahead >= 2)      wait_vm<2 * L>();
        else if (ahead == 1) wait_vm<L>();
        else                 wait_vm<0>();
        __builtin_amdgcn_s_barrier();
        SB0;

        const int buf = t & 3;
        const bf16* ab = lds + buf * (AE + BE);
        const bf16* bb = ab + AE;
        bf16x8 bfr[NI], afr[MI];
        #pragma unroll
        for (int j = 0; j < NI; ++j)
            bfr[j] = *reinterpret_cast<const bf16x8*>(&bb[boff[j]]);
        #pragma unroll
        for (int i = 0; i < MI; ++i)
            afr[i] = *reinterpret_cast<const bf16x8*>(&ab[aoff[i]]);
        asm volatile("s_waitcnt lgkmcnt(0)" ::: "memory");
        SB0;
        if (t + 3 < NT) { stage(t + 3); }
        SB0;
        __builtin_amdgcn_s_setprio(1);
        #pragma unroll
        for (int i = 0; i < MI; ++i)
            #pragma unroll
            for (int j = 0; j < NI; ++j)
                acc[i][j] = mfma16(afr[i], bfr[j], acc[i][j]);
        __builtin_amdgcn_s_setprio(0);
        SB0;
    }

    #pragma unroll
    for (int i = 0; i < MI; ++i) {
        const int mf = bm + wr * 128 + i * 16 + ls4 * 4;
        #pragma unroll
        for (int j = 0; j < NI; ++j) {
            const int nn = bn + wc * WN + j * 16 + lr;
            const f32x4 a = acc[i][j];
            if constexpr (EPI == 5) {
                #pragma unroll
                for (int r = 0; r < 4; ++r) {
                    const float s = siluf(a[r] + e0[mf + r]);
                    Oz[(size_t)(mf + r) * ldo + nn] = (bf16)s;
                }
            } else if constexpr (EPI == 6) {
                #pragma unroll
                for (int r = 0; r < 4; ++r) {
                    const float s = siluf(a[r] + e0[nn]);
                    Oz[(size_t)(mf + r) * ldo + nn] = (bf16)s;
                }
            } else if constexpr (EPI == 3) {
                #pragma unroll
                for (int r = 0; r < 4; ++r) {
                    const float g = (float)Gz[(size_t)(mf + r) * ldg + nn];
                    Oz[(size_t)(mf + r) * ldo + nn] = (bf16)(a[r] * g);
                }
            } else {
                #pragma unroll
                for (int r = 0; r < 4; ++r)
                    F[(size_t)(mf + r) * ldf + nn] = a[r] + e0[nn];
            }
        }
    }
}

// =====================================================================
// gmm8: split-K out-projection GEMM.  BM=256, BN=128, BK=32, 512 thr,
// ring-3 LDS (72 KB -> 2 blocks/CU), lead-2 counted waits -- the EXACT
// loop semantics proven bit-identical in rounds 10/11 (gmm5/gmm6):
//   [wait_vm(L|0); barrier; ds_read(t); lgkm0; stage(t+2); MFMA(t)]
// WAR: stage(t+2) overwrites buf[(t-1)%3]; all iter-(t-1) reads completed
// before any wave passed barrier t.  RAW: wait_vm(L=3) retires tile t.
// z = K-half (sA=sB=1024 elem offsets); partial fp32 -> F + z*sF (no bias).
// =====================================================================
__global__ __launch_bounds__(512) void gmm8(
    const bf16* __restrict__ A, int lda, long long sA,
    const bf16* __restrict__ B, int ldb, long long sB,
    float* __restrict__ F, int ldf, long long sF,
    int K) {

    constexpr int BM = 256, BN = 128, BK = 32;
    constexpr int AE = BM * BK;            // 8192
    constexpr int BE = BN * BK;            // 4096
    constexpr int TE = AE + BE;            // 12288 elems = 24 KB
    constexpr int CHA = 2, CHB = 1, L = 3;
    constexpr int MI = 8, NI = 2;          // wave tile 128 x 32 (2Mx4N waves)

    __shared__ __align__(16) bf16 lds[3 * TE];   // 72 KB

    const int z = blockIdx.z;
    A += (size_t)sA * z;
    B += (size_t)sB * z;
    float* Fz = F + (size_t)sF * z;

    const int tid = threadIdx.x;
    const int l = tid & 63, w = tid >> 6;
    const int wr = w >> 2, wc = w & 3;
    const int lr = l & 15, ls4 = l >> 4;
    const int bm = blockIdx.y * BM, bn = blockIdx.x * BN;

    const bf16* aptr[CHA];
    #pragma unroll
    for (int c = 0; c < CHA; ++c) {
        const int flat = c * 512 + tid;
        const int row = flat >> 2;
        const int slot = (flat & 3) ^ ((row >> 1) & 3);
        aptr[c] = A + (size_t)(bm + row) * lda + slot * 8;
    }
    const bf16* bptr;
    {
        const int row = tid >> 2;
        const int slot = (tid & 3) ^ ((row >> 1) & 3);
        bptr = B + (size_t)(bn + row) * ldb + slot * 8;
    }

    int aoff[MI], boff[NI];
    #pragma unroll
    for (int i = 0; i < MI; ++i) {
        const int row = wr * 128 + i * 16 + lr;
        aoff[i] = row * BK + (ls4 ^ ((row >> 1) & 3)) * 8;
    }
    #pragma unroll
    for (int j = 0; j < NI; ++j) {
        const int row = wc * 32 + j * 16 + lr;
        boff[j] = row * BK + (ls4 ^ ((row >> 1) & 3)) * 8;
    }

    const int NT = K / BK;
    f32x4 acc[MI][NI] = {};

    auto stage = [&](int tile) {
        bf16* ab = lds + (tile % 3) * TE;
        bf16* bb = ab + AE;
        #pragma unroll
        for (int c = 0; c < CHA; ++c)
            gload16(aptr[c] + (size_t)tile * BK, ab + (c * 512 + w * 64) * 8);
        gload16(bptr + (size_t)tile * BK, bb + w * 64 * 8);
    };

    stage(0); SB0;
    stage(1); SB0;

    for (int t = 0; t < NT; ++t) {
        if (t + 1 < NT) wait_vm<L>();      // retire tile t; t+1 stays in flight
        else            wait_vm<0>();
        __builtin_amdgcn_s_barrier();
        SB0;

        const bf16* ab = lds + (t % 3) * TE;
        const bf16* bb = ab + AE;
        bf16x8 afr[MI], bfr[NI];
        #pragma unroll
        for (int j = 0; j < NI; ++j)
            bfr[j] = *reinterpret_cast<const bf16x8*>(&bb[boff[j]]);
        #pragma unroll
        for (int i = 0; i < MI; ++i)
            afr[i] = *reinterpret_cast<const bf16x8*>(&ab[aoff[i]]);
        asm volatile("s_waitcnt lgkmcnt(0)" ::: "memory");
        SB0;
        if (t + 2 < NT) { stage(t + 2); }  // overwrites buf[(t-1)%3]: safe
        SB0;
        __builtin_amdgcn_s_setprio(1);
        #pragma unroll
        for (int i = 0; i < MI; ++i)
            #pragma unroll
            for (int j = 0; j < NI; ++j)
                acc[i][j] = mfma16(afr[i], bfr[j], acc[i][j]);
        __builtin_amdgcn_s_setprio(0);
        SB0;
    }

    #pragma unroll
    for (int i = 0; i < MI; ++i) {
        const int mf = bm + wr * 128 + i * 16 + ls4 * 4;
        #pragma unroll
        for (int j = 0; j < NI; ++j) {
            const int nn = bn + wc * 32 + j * 16 + lr;
            const f32x4 a = acc[i][j];
            #pragma unroll
            for (int r = 0; r < 4; ++r)
                Fz[(size_t)(mf + r) * ldf + nn] = a[r];
        }
    }
}

// ---------------- round-4/13 2-barrier kernel: qk (EPI1) and sim (EPI2) ----------
template<int EPI, bool SPLIT, int MI, int NI>
__global__ __launch_bounds__(256) void gmm(
    const bf16* __restrict__ Ah, const bf16* __restrict__ Al, int lda, long long sA,
    const bf16* __restrict__ Bh, const bf16* __restrict__ Bl, int ldb, long long sB,
    bf16* __restrict__ O, int ldo, long long sO,
    bf16* __restrict__ O2, bf16* __restrict__ O3, bf16* __restrict__ O4,
    const float* __restrict__ e0, const float* __restrict__ e1, const float* __restrict__ e2,
    int K, float scale) {

    constexpr int TM = MI * 32, TN = NI * 32;
    constexpr int CHA = TM / 64, CHB = TN / 64;
    __shared__ __align__(16) bf16 As[TM * 32];
    __shared__ __align__(16) bf16 Bs[TN * 32];

    const int z = blockIdx.z;
    Ah += (size_t)sA * z;
    if (SPLIT) Al += (size_t)sA * z;
    Bh += (size_t)sB * z;
    if (SPLIT) Bl += (size_t)sB * z;
    if (O) O += (size_t)sO * z;

    const int t = threadIdx.x;
    const int l = t & 63, w = t >> 6;
    const int wr = w >> 1, wc = w & 1;
    const int lr = l & 15, ls = l >> 4;
    const int bm = blockIdx.y * TM, bn = blockIdx.x * TN;

    f32x4 acc[MI][NI] = {};
    const int KT = SPLIT ? 3 * K : K;

    for (int k0 = 0; k0 < KT; k0 += 32) {
        const bf16 *pA, *pB;
        int kin;
        if constexpr (SPLIT) {
            if (k0 < K)          { pA = Ah; pB = Bh; kin = k0; }
            else if (k0 < 2 * K) { pA = Al; pB = Bh; kin = k0 - K; }
            else                 { pA = Ah; pB = Bl; kin = k0 - 2 * K; }
        } else { pA = Ah; pB = Bh; kin = k0; }

        #pragma unroll
        for (int c = 0; c < CHA; ++c) {
            const int idx = c * 256 + w * 64 + l;
            const int row = idx >> 2;
            const int sg = (idx & 3) ^ ((row >> 1) & 3);
            gload16(pA + (size_t)(bm + row) * lda + kin + sg * 8,
                    As + (size_t)(c * 256 + w * 64) * 8);
        }
        #pragma unroll
        for (int c = 0; c < CHB; ++c) {
            const int idx = c * 256 + w * 64 + l;
            const int row = idx >> 2;
            const int sg = (idx & 3) ^ ((row >> 1) & 3);
            gload16(pB + (size_t)(bn + row) * ldb + kin + sg * 8,
                    Bs + (size_t)(c * 256 + w * 64) * 8);
        }
        __syncthreads();

        bf16x8 bfr[NI];
        #pragma unroll
        for (int j = 0; j < NI; ++j) {
            const int row = wc * (NI * 16) + j * 16 + lr;
            const int sl = ls ^ ((row >> 1) & 3);
            bfr[j] = *reinterpret_cast<const bf16x8*>(&Bs[row * 32 + sl * 8]);
        }
        #pragma unroll
        for (int i = 0; i < MI; ++i) {
            const int row = wr * (MI * 16) + i * 16 + lr;
            const int sl = ls ^ ((row >> 1) & 3);
            const bf16x8 af = *reinterpret_cast<const bf16x8*>(&As[row * 32 + sl * 8]);
            #pragma unroll
            for (int j = 0; j < NI; ++j)
                acc[i][j] = mfma16(af, bfr[j], acc[i][j]);
        }
        __syncthreads();
    }

    #pragma unroll
    for (int i = 0; i < MI; ++i) {
        const int mf = bm + wr * (MI * 16) + i * 16 + ls * 4;
        #pragma unroll
        for (int j = 0; j < NI; ++j) {
            const int nn = bn + wc * (NI * 16) + j * 16 + lr;
            const f32x4 a = acc[i][j];
            if constexpr (EPI == 1) {
                #pragma unroll
                for (int r = 0; r < 4; ++r) {
                    const float s = siluf(a[r] + e0[nn]);
                    const float q = s * e1[nn] + e2[nn];
                    const float k = s * e1[QKD + nn] + e2[QKD + nn];
                    bf16 h, lo;
                    splitf(q, h, lo);
                    O[(size_t)(mf + r) * ldo + nn] = h;  O2[(size_t)(mf + r) * ldo + nn] = lo;
                    splitf(k, h, lo);
                    O3[(size_t)(mf + r) * ldo + nn] = h; O4[(size_t)(mf + r) * ldo + nn] = lo;
                }
            } else if constexpr (EPI == 2) {
                #pragma unroll
                for (int r = 0; r < 4; ++r) {
                    const float tv = a[r] * scale;
                    const float p = tv > 0.f ? tv * tv : 0.f;
                    O[(size_t)(mf + r) * ldo + nn] = (bf16)p;
                }
            }
        }
    }
}

extern "C" void kernel_launch(void* const* d_in, const int* in_sizes, int n_in,
                              void* d_out, int out_size, void* d_ws, size_t ws_size,
                              hipStream_t stream) {
    const float* x        = (const float*)d_in[0];
    const float* ln_scale = (const float*)d_in[1];
    const float* ln_bias  = (const float*)d_in[2];
    const float* W_hidden = (const float*)d_in[3];
    const float* b_hidden = (const float*)d_in[4];
    const float* W_qk     = (const float*)d_in[5];
    const float* b_qk     = (const float*)d_in[6];
    const float* os_w     = (const float*)d_in[7];
    const float* os_b     = (const float*)d_in[8];
    const float* W_out    = (const float*)d_in[9];
    const float* b_out    = (const float*)d_in[10];
    float* out = (float*)d_out;

    // ---- weight prep area ----
    char* p = (char*)d_ws;
    bf16* WhTh  = (bf16*)p; p += (size_t)4096 * 1024 * 2;   // [4096][1024]
    bf16* WqkTh = (bf16*)p; p += (size_t)128 * 1024 * 2;    // [128][1024] hi
    bf16* WqkTl = (bf16*)p; p += (size_t)128 * 1024 * 2;    // lo
    bf16* WoTh  = (bf16*)p; p += (size_t)1024 * 2048 * 2;   // [1024][2048]

    wsplitT<<<dim3(4096 / 32, 1024 / 32), 256, 0, stream>>>(W_hidden, 1024, 4096, WhTh, nullptr);
    wsplitT<<<dim3(128 / 32, 1024 / 32), 256, 0, stream>>>(W_qk, 1024, 128, WqkTh, WqkTl);
    wsplitT<<<dim3(1024 / 32, 2048 / 32), 256, 0, stream>>>(W_out, 2048, 1024, WoTh, nullptr);

    const size_t used = (size_t)(p - (char*)d_ws);
    const size_t qkB   = (size_t)4 * 8192 * 128 * 2;
    const size_t vTB   = (size_t)2048 * 8192 * 2;
    const size_t gateB = (size_t)8192 * 2048 * 2;
    const size_t attnB = (size_t)4 * 2048 * 2048 * 2;
    const size_t yB    = (size_t)8192 * 2048 * 2;
    const bool allb = (ws_size >= used + qkB + vTB + gateB + attnB + yB + (1u << 20));

    if (allb) {
        bf16* xh = (bf16*)out;                      // d_out doubles as xn hi/lo
        bf16* xl = xh + (size_t)8192 * 1024;
        bf16* qh   = (bf16*)p; p += (size_t)8192 * 128 * 2;
        bf16* ql   = (bf16*)p; p += (size_t)8192 * 128 * 2;
        bf16* kh   = (bf16*)p; p += (size_t)8192 * 128 * 2;
        bf16* kl   = (bf16*)p; p += (size_t)8192 * 128 * 2;
        bf16* vT   = (bf16*)p; p += vTB;            // [2048][8192]  (n, m)
        bf16* gate = (bf16*)p; p += gateB;          // [8192][2048]  (m, n')
        bf16* attn = (bf16*)p; p += attnB;          // [4][2048][2048]
        bf16* y    = (bf16*)p; p += yB;             // [8192][2048]

        // out-projection partials alias the dead-after-av region (qh..gate: 72 MB >= 67.1)
        float* outp0 = (float*)qh;
        float* outp1 = outp0 + (size_t)8192 * 1024;

        ln_split<<<8192, 256, 0, stream>>>(x, ln_scale, ln_bias, xh, xl);

        // hid-v (FLIPPED): vT[2048][8192] = silu(WhT[0:2048] . xh^T + b_v)
        gmm2<5, 256><<<dim3(8192 / 256, 2048 / 256), 512, 0, stream>>>(
            WhTh, 1024, 0, xh, 1024, 0,
            vT, 8192, 0, nullptr, 0, 0,
            nullptr, 0, b_hidden, 1024);

        // hid-gate (natural): gate[8192][2048] = silu(xh . Wh[:,2048:] + b_g)
        gmm2<6, 256><<<dim3(2048 / 256, 8192 / 256), 512, 0, stream>>>(
            xh, 1024, 0, WhTh + (size_t)2048 * 1024, 1024, 0,
            gate, 2048, 0, nullptr, 0, 0,
            nullptr, 0, b_hidden + HIDD, 1024);

        // qk (split): [8192 x 128] -> q,k hi/lo
        gmm<1, true, 2, 2><<<dim3(128 / 64, 8192 / 64), 256, 0, stream>>>(
            xh, xl, 1024, 0, WqkTh, WqkTl, 1024, 0,
            qh, 128, 0, ql, kh, kl,
            b_qk, os_w, os_b, 1024, 0.f);

        // sim (split): per-batch [2048 x 2048]
        gmm<2, true, 4, 4><<<dim3(16, 16, 4), 256, 0, stream>>>(
            qh, ql, 128, (long long)2048 * 128, kh, kl, 128, (long long)2048 * 128,
            attn, 2048, (long long)2048 * 2048, nullptr, nullptr, nullptr,
            nullptr, nullptr, nullptr, 128, 1.0f / SEQ);

        // av: y[m][n] = (attn @ v) * gate[m][n]   per batch
        gmm2<3, 256><<<dim3(2048 / 256, 2048 / 256, 4), 512, 0, stream>>>(
            attn, 2048, (long long)2048 * 2048, vT, 8192, 2048,
            y, 2048, (long long)2048 * 2048, gate, 2048, (long long)2048 * 2048,
            nullptr, 0, nullptr, 2048);

        // out split-K: partials over K halves (z in {0,1}), 512 blocks, 2 blk/CU
        gmm8<<<dim3(1024 / 128, 8192 / 256, 2), 512, 0, stream>>>(
            y, 2048, 1024, WoTh, 2048, 1024,
            outp0, 1024, (long long)8192 * 1024, 1024);

        // out = p0 + p1 + b_out
        addbias<<<2048, 256, 0, stream>>>(outp0, outp1, b_out, out, 8192 * 1024 / 4);
    } else {
        // ---------------- per-batch fallback (round-13 proven path) ----------------
        bf16* xh = (bf16*)p; p += (size_t)8192 * 1024 * 2;
        bf16* xl = (bf16*)p; p += (size_t)8192 * 1024 * 2;
        bf16* qh   = (bf16*)p; p += (size_t)2048 * 128 * 2;
        bf16* ql   = (bf16*)p; p += (size_t)2048 * 128 * 2;
        bf16* kh   = (bf16*)p; p += (size_t)2048 * 128 * 2;
        bf16* kl   = (bf16*)p; p += (size_t)2048 * 128 * 2;
        bf16* vT   = (bf16*)p; p += (size_t)2048 * 2048 * 2;   // [2048 n][2048 m]
        bf16* gate = (bf16*)p; p += (size_t)2048 * 2048 * 2;   // [2048 m][2048 n']
        bf16* attn = (bf16*)p; p += (size_t)2048 * 2048 * 2;
        bf16* y    = (bf16*)p; p += (size_t)2048 * 2048 * 2;

        ln_split<<<8192, 256, 0, stream>>>(x, ln_scale, ln_bias, xh, xl);

        for (int b = 0; b < BATCH; ++b) {
            const bf16* xhb = xh + (size_t)b * 2048 * 1024;
            const bf16* xlb = xl + (size_t)b * 2048 * 1024;

            gmm2<5, 256><<<dim3(2048 / 256, 2048 / 256), 512, 0, stream>>>(
                WhTh, 1024, 0, xhb, 1024, 0,
                vT, 2048, 0, nullptr, 0, 0,
                nullptr, 0, b_hidden, 1024);

            gmm2<6, 256><<<dim3(2048 / 256, 2048 / 256), 512, 0, stream>>>(
                xhb, 1024, 0, WhTh + (size_t)2048 * 1024, 1024, 0,
                gate, 2048, 0, nullptr, 0, 0,
                nullptr, 0, b_hidden + HIDD, 1024);

            gmm<1, true, 2, 2><<<dim3(128 / 64, 2048 / 64), 256, 0, stream>>>(
                xhb, xlb, 1024, 0, WqkTh, WqkTl, 1024, 0,
                qh, 128, 0, ql, kh, kl,
                b_qk, os_w, os_b, 1024, 0.f);

            gmm<2, true, 4, 4><<<dim3(16, 16, 1), 256, 0, stream>>>(
                qh, ql, 128, 0, kh, kl, 128, 0,
                attn, 2048, 0, nullptr, nullptr, nullptr,
                nullptr, nullptr, nullptr, 128, 1.0f / SEQ);

            gmm2<3, 256><<<dim3(2048 / 256, 2048 / 256, 1), 512, 0, stream>>>(
                attn, 2048, 0, vT, 2048, 0,
                y, 2048, 0, gate, 2048, 0,
                nullptr, 0, nullptr, 2048);

            gmm2<4, 128><<<dim3(1024 / 128, 2048 / 256), 512, 0, stream>>>(
                y, 2048, 0, WoTh, 2048, 0,
                nullptr, 0, 0, nullptr, 0, 0,
                out + (size_t)b * 2048 * 1024, 1024, b_out, 2048);
        }
    }
}

// Round 17
// 289.804 us; speedup vs baseline: 1.1000x; 1.1000x over previous
//
#include <hip/hip_runtime.h>
#include <math.h>

#define DIMX 1024
#define QKD  128
#define HIDD 2048
#define BATCH 4
#define SEQ  2048

typedef __bf16 bf16;
typedef __bf16 bf16x8 __attribute__((ext_vector_type(8)));
typedef __bf16 bf16x4v __attribute__((ext_vector_type(4)));
typedef float f32x4 __attribute__((ext_vector_type(4)));

__device__ __forceinline__ float siluf(float v) { return v / (1.f + expf(-v)); }
__device__ __forceinline__ void splitf(float x, bf16& h, bf16& l) {
    h = (bf16)x;
    l = (bf16)(x - (float)h);
}
__device__ __forceinline__ f32x4 mfma16(bf16x8 a, bf16x8 b, f32x4 c) {
    return __builtin_amdgcn_mfma_f32_16x16x32_bf16(a, b, c, 0, 0, 0);
}

typedef __attribute__((address_space(1))) const void cg_void;
typedef __attribute__((address_space(3))) void lds_void_t;
__device__ __forceinline__ void gload16(const bf16* g, bf16* l) {
    __builtin_amdgcn_global_load_lds((cg_void*)g, (lds_void_t*)l, 16, 0, 0);
}

template<int N> __device__ __forceinline__ void wait_vm() {
    if constexpr (N == 0)  asm volatile("s_waitcnt vmcnt(0)" ::: "memory");
    if constexpr (N == 3)  asm volatile("s_waitcnt vmcnt(3)" ::: "memory");
    if constexpr (N == 4)  asm volatile("s_waitcnt vmcnt(4)" ::: "memory");
    if constexpr (N == 6)  asm volatile("s_waitcnt vmcnt(6)" ::: "memory");
    if constexpr (N == 8)  asm volatile("s_waitcnt vmcnt(8)" ::: "memory");
}

#define SB0 __builtin_amdgcn_sched_barrier(0)

// -------------------- LayerNorm -> split bf16 hi/lo --------------------
__global__ __launch_bounds__(256) void ln_split(const float* __restrict__ x,
                                                const float* __restrict__ scale,
                                                const float* __restrict__ bias,
                                                bf16* __restrict__ xh,
                                                bf16* __restrict__ xl) {
    const int row = blockIdx.x;
    const float4 v = reinterpret_cast<const float4*>(x + (size_t)row * DIMX)[threadIdx.x];
    float s  = v.x + v.y + v.z + v.w;
    float ss = v.x * v.x + v.y * v.y + v.z * v.z + v.w * v.w;
    #pragma unroll
    for (int off = 32; off; off >>= 1) {
        s  += __shfl_down(s, off);
        ss += __shfl_down(ss, off);
    }
    __shared__ float ls[4], lss[4];
    const int wid = threadIdx.x >> 6, lane = threadIdx.x & 63;
    if (lane == 0) { ls[wid] = s; lss[wid] = ss; }
    __syncthreads();
    if (threadIdx.x == 0) {
        float a = ls[0] + ls[1] + ls[2] + ls[3];
        float b = lss[0] + lss[1] + lss[2] + lss[3];
        float mu  = a / DIMX;
        float var = b / DIMX - mu * mu;
        ls[0]  = mu;
        lss[0] = rsqrtf(var + 1e-5f);
    }
    __syncthreads();
    const float mu = ls[0], rs = lss[0];
    const float4 sc = reinterpret_cast<const float4*>(scale)[threadIdx.x];
    const float4 bi = reinterpret_cast<const float4*>(bias)[threadIdx.x];
    float o[4];
    o[0] = (v.x - mu) * rs * sc.x + bi.x;
    o[1] = (v.y - mu) * rs * sc.y + bi.y;
    o[2] = (v.z - mu) * rs * sc.z + bi.z;
    o[3] = (v.w - mu) * rs * sc.w + bi.w;
    bf16x4v h, l;
    #pragma unroll
    for (int i = 0; i < 4; ++i) { bf16 hh, ll; splitf(o[i], hh, ll); h[i] = hh; l[i] = ll; }
    *reinterpret_cast<bf16x4v*>(xh + (size_t)row * DIMX + threadIdx.x * 4) = h;
    *reinterpret_cast<bf16x4v*>(xl + (size_t)row * DIMX + threadIdx.x * 4) = l;
}

// ------------- transpose + split: W [K][N] fp32 -> T[N][K] bf16 hi(/lo) -------------
__global__ __launch_bounds__(256) void wsplitT(const float* __restrict__ W, int K, int N,
                                               bf16* __restrict__ Th, bf16* __restrict__ Tl) {
    __shared__ float tile[32][33];
    const int bx = blockIdx.x * 32;   // N dir
    const int by = blockIdx.y * 32;   // K dir
    const int tx = threadIdx.x & 31, ty = threadIdx.x >> 5;
    #pragma unroll
    for (int r = 0; r < 32; r += 8)
        tile[ty + r][tx] = W[(size_t)(by + ty + r) * N + bx + tx];
    __syncthreads();
    #pragma unroll
    for (int r = 0; r < 32; r += 8) {
        const float v = tile[tx][ty + r];
        bf16 h, l; splitf(v, h, l);
        Th[(size_t)(bx + ty + r) * K + by + tx] = h;
        if (Tl) Tl[(size_t)(bx + ty + r) * K + by + tx] = l;
    }
}

// =====================================================================
// gmm2: ring-buffered MFMA GEMM (round-9 proven, single-barrier loop).
// BM=256, BK=32, 512 threads (8 waves 2Mx4N), 4-deep LDS ring.
// Loop: [wait_vm(2L|L|0); barrier; ds_read(t); lgkm0; stage(t+3); MFMA(t)].
// WAR: stage(t+3) overwrites buf[(t-1)&3]; all iter-(t-1) reads completed
// before any wave passed barrier t.  RAW: wait_vm(2L) retires tile t.
// SPLIT (sim only, K=128): 3-product hi/lo over tile index tt=0..11;
// slice = tt>>2 (4 tiles/slice), kin = (tt&3)*BK; slices (Ah,Bh),(Al,Bh),
// (Ah,Bl) -- same accumulation order as the proven 2-barrier split loop.
// Slice selection only changes the staged global address; ring/wait
// accounting identical.
// Epilogues (ALL natural row-major stores):
// EPI 5 (hid vT half, FLIPPED): rows=n; O[n][m]=silu(acc+e0[row])
// EPI 6 (hid gate half):        rows=m; O[m][n']=silu(acc+e0[n'])
// EPI 2 (sim):  O[m][n] = relu(acc*scale)^2  bf16
// EPI 3 (av):   y[m][n] = acc * G[m][n]  bf16
// EPI 4 (out):  F[m][n] = acc + e0[n]  fp32
// =====================================================================
template<int EPI, int BN, bool SPLIT = false>
__global__ __launch_bounds__(512) void gmm2(
    const bf16* __restrict__ A, const bf16* __restrict__ Al, int lda, long long sA,
    const bf16* __restrict__ B, const bf16* __restrict__ Bl, int ldb, long long sB,
    bf16* __restrict__ O, int ldo, long long sO,
    bf16* __restrict__ G, int ldg, long long sG,
    float* __restrict__ F, int ldf,
    const float* __restrict__ e0,
    int K, float scale) {

    constexpr int BM = 256, BK = 32;
    constexpr int AE = BM * BK;
    constexpr int BE = BN * BK;
    constexpr int CHA = AE / (512 * 8);
    constexpr int CHB = BE / (512 * 8);
    constexpr int L = CHA + CHB;
    constexpr int WN = BN / 4;
    constexpr int MI = 8, NI = WN / 16;

    __shared__ __align__(16) bf16 lds[4 * (AE + BE)];

    const int z = blockIdx.z;
    A += (size_t)sA * z;
    B += (size_t)sB * z;
    if (SPLIT) { Al += (size_t)sA * z; Bl += (size_t)sB * z; }
    bf16* Oz = O ? O + (size_t)sO * z : nullptr;
    bf16* Gz = G ? G + (size_t)sG * z : nullptr;

    const int tid = threadIdx.x;
    const int l = tid & 63, w = tid >> 6;
    const int wr = w >> 2, wc = w & 3;
    const int lr = l & 15, ls4 = l >> 4;
    const int bm = blockIdx.y * BM, bn = blockIdx.x * BN;

    // per-thread staging offsets within the A/B panels (slot-XOR pre-swizzled)
    size_t aoffg[CHA], boffg[CHB];
    #pragma unroll
    for (int c = 0; c < CHA; ++c) {
        const int flat = c * 512 + tid;
        const int row = flat >> 2;
        const int slot = (flat & 3) ^ ((row >> 1) & 3);
        aoffg[c] = (size_t)(bm + row) * lda + slot * 8;
    }
    #pragma unroll
    for (int c = 0; c < CHB; ++c) {
        const int flat = c * 512 + tid;
        const int row = flat >> 2;
        const int slot = (flat & 3) ^ ((row >> 1) & 3);
        boffg[c] = (size_t)(bn + row) * ldb + slot * 8;
    }

    int aoff[MI], boff[NI];
    #pragma unroll
    for (int i = 0; i < MI; ++i) {
        const int row = wr * 128 + i * 16 + lr;
        aoff[i] = row * BK + (ls4 ^ ((row >> 1) & 3)) * 8;
    }
    #pragma unroll
    for (int j = 0; j < NI; ++j) {
        const int row = wc * WN + j * 16 + lr;
        boff[j] = row * BK + (ls4 ^ ((row >> 1) & 3)) * 8;
    }

    const int NT = SPLIT ? 3 * (K / BK) : K / BK;   // SPLIT: K=128 -> NT=12
    f32x4 acc[MI][NI] = {};

    auto stage = [&](int tt) {
        const int buf = tt & 3;
        bf16* ab = lds + buf * (AE + BE);
        bf16* bb = ab + AE;
        const bf16 *pA = A, *pB = B;
        size_t kin;
        if constexpr (SPLIT) {
            const int sl = tt >> 2;          // K=128: 4 tiles per slice
            kin = (size_t)(tt & 3) * BK;
            if (sl == 1) pA = Al;
            else if (sl == 2) pB = Bl;
        } else {
            kin = (size_t)tt * BK;
        }
        #pragma unroll
        for (int c = 0; c < CHA; ++c)
            gload16(pA + aoffg[c] + kin, ab + (c * 512 + w * 64) * 8);
        #pragma unroll
        for (int c = 0; c < CHB; ++c)
            gload16(pB + boffg[c] + kin, bb + (c * 512 + w * 64) * 8);
    };

    stage(0); SB0;
    stage(1); SB0;
    stage(2); SB0;

    for (int t = 0; t < NT; ++t) {
        const int ahead = NT - 1 - t;
        if (ahead >= 2)      wait_vm<2 * L>();
        else if (ahead == 1) wait_vm<L>();
        else                 wait_vm<0>();
        __builtin_amdgcn_s_barrier();
        SB0;

        const int buf = t & 3;
        const bf16* ab = lds + buf * (AE + BE);
        const bf16* bb = ab + AE;
        bf16x8 bfr[NI], afr[MI];
        #pragma unroll
        for (int j = 0; j < NI; ++j)
            bfr[j] = *reinterpret_cast<const bf16x8*>(&bb[boff[j]]);
        #pragma unroll
        for (int i = 0; i < MI; ++i)
            afr[i] = *reinterpret_cast<const bf16x8*>(&ab[aoff[i]]);
        asm volatile("s_waitcnt lgkmcnt(0)" ::: "memory");
        SB0;
        if (t + 3 < NT) { stage(t + 3); }
        SB0;
        __builtin_amdgcn_s_setprio(1);
        #pragma unroll
        for (int i = 0; i < MI; ++i)
            #pragma unroll
            for (int j = 0; j < NI; ++j)
                acc[i][j] = mfma16(afr[i], bfr[j], acc[i][j]);
        __builtin_amdgcn_s_setprio(0);
        SB0;
    }

    #pragma unroll
    for (int i = 0; i < MI; ++i) {
        const int mf = bm + wr * 128 + i * 16 + ls4 * 4;
        #pragma unroll
        for (int j = 0; j < NI; ++j) {
            const int nn = bn + wc * WN + j * 16 + lr;
            const f32x4 a = acc[i][j];
            if constexpr (EPI == 5) {
                #pragma unroll
                for (int r = 0; r < 4; ++r) {
                    const float s = siluf(a[r] + e0[mf + r]);
                    Oz[(size_t)(mf + r) * ldo + nn] = (bf16)s;
                }
            } else if constexpr (EPI == 6) {
                #pragma unroll
                for (int r = 0; r < 4; ++r) {
                    const float s = siluf(a[r] + e0[nn]);
                    Oz[(size_t)(mf + r) * ldo + nn] = (bf16)s;
                }
            } else if constexpr (EPI == 2) {
                #pragma unroll
                for (int r = 0; r < 4; ++r) {
                    const float tv = a[r] * scale;
                    const float pv = tv > 0.f ? tv * tv : 0.f;
                    Oz[(size_t)(mf + r) * ldo + nn] = (bf16)pv;
                }
            } else if constexpr (EPI == 3) {
                #pragma unroll
                for (int r = 0; r < 4; ++r) {
                    const float g = (float)Gz[(size_t)(mf + r) * ldg + nn];
                    Oz[(size_t)(mf + r) * ldo + nn] = (bf16)(a[r] * g);
                }
            } else {
                #pragma unroll
                for (int r = 0; r < 4; ++r)
                    F[(size_t)(mf + r) * ldf + nn] = a[r] + e0[nn];
            }
        }
    }
}

// ---------------- round-4/13 2-barrier kernel: qk projection (EPI1) ----------
template<int EPI, bool SPLIT, int MI, int NI>
__global__ __launch_bounds__(256) void gmm(
    const bf16* __restrict__ Ah, const bf16* __restrict__ Al, int lda, long long sA,
    const bf16* __restrict__ Bh, const bf16* __restrict__ Bl, int ldb, long long sB,
    bf16* __restrict__ O, int ldo, long long sO,
    bf16* __restrict__ O2, bf16* __restrict__ O3, bf16* __restrict__ O4,
    const float* __restrict__ e0, const float* __restrict__ e1, const float* __restrict__ e2,
    int K, float scale) {

    constexpr int TM = MI * 32, TN = NI * 32;
    constexpr int CHA = TM / 64, CHB = TN / 64;
    __shared__ __align__(16) bf16 As[TM * 32];
    __shared__ __align__(16) bf16 Bs[TN * 32];

    const int z = blockIdx.z;
    Ah += (size_t)sA * z;
    if (SPLIT) Al += (size_t)sA * z;
    Bh += (size_t)sB * z;
    if (SPLIT) Bl += (size_t)sB * z;
    if (O) O += (size_t)sO * z;

    const int t = threadIdx.x;
    const int l = t & 63, w = t >> 6;
    const int wr = w >> 1, wc = w & 1;
    const int lr = l & 15, ls = l >> 4;
    const int bm = blockIdx.y * TM, bn = blockIdx.x * TN;

    f32x4 acc[MI][NI] = {};
    const int KT = SPLIT ? 3 * K : K;

    for (int k0 = 0; k0 < KT; k0 += 32) {
        const bf16 *pA, *pB;
        int kin;
        if constexpr (SPLIT) {
            if (k0 < K)          { pA = Ah; pB = Bh; kin = k0; }
            else if (k0 < 2 * K) { pA = Al; pB = Bh; kin = k0 - K; }
            else                 { pA = Ah; pB = Bl; kin = k0 - 2 * K; }
        } else { pA = Ah; pB = Bh; kin = k0; }

        #pragma unroll
        for (int c = 0; c < CHA; ++c) {
            const int idx = c * 256 + w * 64 + l;
            const int row = idx >> 2;
            const int sg = (idx & 3) ^ ((row >> 1) & 3);
            gload16(pA + (size_t)(bm + row) * lda + kin + sg * 8,
                    As + (size_t)(c * 256 + w * 64) * 8);
        }
        #pragma unroll
        for (int c = 0; c < CHB; ++c) {
            const int idx = c * 256 + w * 64 + l;
            const int row = idx >> 2;
            const int sg = (idx & 3) ^ ((row >> 1) & 3);
            gload16(pB + (size_t)(bn + row) * ldb + kin + sg * 8,
                    Bs + (size_t)(c * 256 + w * 64) * 8);
        }
        __syncthreads();

        bf16x8 bfr[NI];
        #pragma unroll
        for (int j = 0; j < NI; ++j) {
            const int row = wc * (NI * 16) + j * 16 + lr;
            const int sl = ls ^ ((row >> 1) & 3);
            bfr[j] = *reinterpret_cast<const bf16x8*>(&Bs[row * 32 + sl * 8]);
        }
        #pragma unroll
        for (int i = 0; i < MI; ++i) {
            const int row = wr * (MI * 16) + i * 16 + lr;
            const int sl = ls ^ ((row >> 1) & 3);
            const bf16x8 af = *reinterpret_cast<const bf16x8*>(&As[row * 32 + sl * 8]);
            #pragma unroll
            for (int j = 0; j < NI; ++j)
                acc[i][j] = mfma16(af, bfr[j], acc[i][j]);
        }
        __syncthreads();
    }

    #pragma unroll
    for (int i = 0; i < MI; ++i) {
        const int mf = bm + wr * (MI * 16) + i * 16 + ls * 4;
        #pragma unroll
        for (int j = 0; j < NI; ++j) {
            const int nn = bn + wc * (NI * 16) + j * 16 + lr;
            const f32x4 a = acc[i][j];
            if constexpr (EPI == 1) {
                #pragma unroll
                for (int r = 0; r < 4; ++r) {
                    const float s = siluf(a[r] + e0[nn]);
                    const float q = s * e1[nn] + e2[nn];
                    const float k = s * e1[QKD + nn] + e2[QKD + nn];
                    bf16 h, lo;
                    splitf(q, h, lo);
                    O[(size_t)(mf + r) * ldo + nn] = h;  O2[(size_t)(mf + r) * ldo + nn] = lo;
                    splitf(k, h, lo);
                    O3[(size_t)(mf + r) * ldo + nn] = h; O4[(size_t)(mf + r) * ldo + nn] = lo;
                }
            }
        }
    }
}

extern "C" void kernel_launch(void* const* d_in, const int* in_sizes, int n_in,
                              void* d_out, int out_size, void* d_ws, size_t ws_size,
                              hipStream_t stream) {
    const float* x        = (const float*)d_in[0];
    const float* ln_scale = (const float*)d_in[1];
    const float* ln_bias  = (const float*)d_in[2];
    const float* W_hidden = (const float*)d_in[3];
    const float* b_hidden = (const float*)d_in[4];
    const float* W_qk     = (const float*)d_in[5];
    const float* b_qk     = (const float*)d_in[6];
    const float* os_w     = (const float*)d_in[7];
    const float* os_b     = (const float*)d_in[8];
    const float* W_out    = (const float*)d_in[9];
    const float* b_out    = (const float*)d_in[10];
    float* out = (float*)d_out;

    // ---- weight prep area ----
    char* p = (char*)d_ws;
    bf16* WhTh  = (bf16*)p; p += (size_t)4096 * 1024 * 2;   // [4096][1024]
    bf16* WqkTh = (bf16*)p; p += (size_t)128 * 1024 * 2;    // [128][1024] hi
    bf16* WqkTl = (bf16*)p; p += (size_t)128 * 1024 * 2;    // lo
    bf16* WoTh  = (bf16*)p; p += (size_t)1024 * 2048 * 2;   // [1024][2048]

    wsplitT<<<dim3(4096 / 32, 1024 / 32), 256, 0, stream>>>(W_hidden, 1024, 4096, WhTh, nullptr);
    wsplitT<<<dim3(128 / 32, 1024 / 32), 256, 0, stream>>>(W_qk, 1024, 128, WqkTh, WqkTl);
    wsplitT<<<dim3(1024 / 32, 2048 / 32), 256, 0, stream>>>(W_out, 2048, 1024, WoTh, nullptr);

    const size_t used = (size_t)(p - (char*)d_ws);
    const size_t qkB   = (size_t)4 * 8192 * 128 * 2;
    const size_t vTB   = (size_t)2048 * 8192 * 2;
    const size_t gateB = (size_t)8192 * 2048 * 2;
    const size_t attnB = (size_t)4 * 2048 * 2048 * 2;
    const size_t yB    = (size_t)8192 * 2048 * 2;
    const bool allb = (ws_size >= used + qkB + vTB + gateB + attnB + yB + (1u << 20));

    if (allb) {
        bf16* xh = (bf16*)out;                      // d_out doubles as xn hi/lo
        bf16* xl = xh + (size_t)8192 * 1024;
        bf16* qh   = (bf16*)p; p += (size_t)8192 * 128 * 2;
        bf16* ql   = (bf16*)p; p += (size_t)8192 * 128 * 2;
        bf16* kh   = (bf16*)p; p += (size_t)8192 * 128 * 2;
        bf16* kl   = (bf16*)p; p += (size_t)8192 * 128 * 2;
        bf16* vT   = (bf16*)p; p += vTB;            // [2048][8192]  (n, m)
        bf16* gate = (bf16*)p; p += gateB;          // [8192][2048]  (m, n')
        bf16* attn = (bf16*)p; p += attnB;          // [4][2048][2048]
        bf16* y    = (bf16*)p; p += yB;             // [8192][2048]

        ln_split<<<8192, 256, 0, stream>>>(x, ln_scale, ln_bias, xh, xl);

        // hid-v (FLIPPED): vT[2048][8192] = silu(WhT[0:2048] . xh^T + b_v)
        gmm2<5, 256><<<dim3(8192 / 256, 2048 / 256), 512, 0, stream>>>(
            WhTh, nullptr, 1024, 0, xh, nullptr, 1024, 0,
            vT, 8192, 0, nullptr, 0, 0,
            nullptr, 0, b_hidden, 1024, 0.f);

        // hid-gate (natural): gate[8192][2048] = silu(xh . Wh[:,2048:] + b_g)
        gmm2<6, 256><<<dim3(2048 / 256, 8192 / 256), 512, 0, stream>>>(
            xh, nullptr, 1024, 0, WhTh + (size_t)2048 * 1024, nullptr, 1024, 0,
            gate, 2048, 0, nullptr, 0, 0,
            nullptr, 0, b_hidden + HIDD, 1024, 0.f);

        // qk (split, round-13 proven): [8192 x 128] -> q,k hi/lo
        gmm<1, true, 2, 2><<<dim3(128 / 64, 8192 / 64), 256, 0, stream>>>(
            xh, xl, 1024, 0, WqkTh, WqkTl, 1024, 0,
            qh, 128, 0, ql, kh, kl,
            b_qk, os_w, os_b, 1024, 0.f);

        // sim (SPLIT ring, K=128 -> 12 tiles): per-batch [2048 x 2048]
        gmm2<2, 256, true><<<dim3(2048 / 256, 2048 / 256, 4), 512, 0, stream>>>(
            qh, ql, 128, (long long)2048 * 128, kh, kl, 128, (long long)2048 * 128,
            attn, 2048, (long long)2048 * 2048, nullptr, 0, 0,
            nullptr, 0, nullptr, 128, 1.0f / SEQ);

        // av: y[m][n] = (attn @ v) * gate[m][n]   per batch
        gmm2<3, 256><<<dim3(2048 / 256, 2048 / 256, 4), 512, 0, stream>>>(
            attn, nullptr, 2048, (long long)2048 * 2048, vT, nullptr, 8192, 2048,
            y, 2048, (long long)2048 * 2048, gate, 2048, (long long)2048 * 2048,
            nullptr, 0, nullptr, 2048, 0.f);

        // out: [8192 x 1024] fp32 -> d_out (round-13 proven)
        gmm2<4, 128><<<dim3(1024 / 128, 8192 / 256), 512, 0, stream>>>(
            y, nullptr, 2048, 0, WoTh, nullptr, 2048, 0,
            nullptr, 0, 0, nullptr, 0, 0,
            out, 1024, b_out, 2048, 0.f);
    } else {
        // ---------------- per-batch fallback ----------------
        bf16* xh = (bf16*)p; p += (size_t)8192 * 1024 * 2;
        bf16* xl = (bf16*)p; p += (size_t)8192 * 1024 * 2;
        bf16* qh   = (bf16*)p; p += (size_t)2048 * 128 * 2;
        bf16* ql   = (bf16*)p; p += (size_t)2048 * 128 * 2;
        bf16* kh   = (bf16*)p; p += (size_t)2048 * 128 * 2;
        bf16* kl   = (bf16*)p; p += (size_t)2048 * 128 * 2;
        bf16* vT   = (bf16*)p; p += (size_t)2048 * 2048 * 2;   // [2048 n][2048 m]
        bf16* gate = (bf16*)p; p += (size_t)2048 * 2048 * 2;   // [2048 m][2048 n']
        bf16* attn = (bf16*)p; p += (size_t)2048 * 2048 * 2;
        bf16* y    = (bf16*)p; p += (size_t)2048 * 2048 * 2;

        ln_split<<<8192, 256, 0, stream>>>(x, ln_scale, ln_bias, xh, xl);

        for (int b = 0; b < BATCH; ++b) {
            const bf16* xhb = xh + (size_t)b * 2048 * 1024;
            const bf16* xlb = xl + (size_t)b * 2048 * 1024;

            gmm2<5, 256><<<dim3(2048 / 256, 2048 / 256), 512, 0, stream>>>(
                WhTh, nullptr, 1024, 0, xhb, nullptr, 1024, 0,
                vT, 2048, 0, nullptr, 0, 0,
                nullptr, 0, b_hidden, 1024, 0.f);

            gmm2<6, 256><<<dim3(2048 / 256, 2048 / 256), 512, 0, stream>>>(
                xhb, nullptr, 1024, 0, WhTh + (size_t)2048 * 1024, nullptr, 1024, 0,
                gate, 2048, 0, nullptr, 0, 0,
                nullptr, 0, b_hidden + HIDD, 1024, 0.f);

            gmm<1, true, 2, 2><<<dim3(128 / 64, 2048 / 64), 256, 0, stream>>>(
                xhb, xlb, 1024, 0, WqkTh, WqkTl, 1024, 0,
                qh, 128, 0, ql, kh, kl,
                b_qk, os_w, os_b, 1024, 0.f);

            gmm2<2, 256, true><<<dim3(2048 / 256, 2048 / 256, 1), 512, 0, stream>>>(
                qh, ql, 128, 0, kh, kl, 128, 0,
                attn, 2048, 0, nullptr, 0, 0,
                nullptr, 0, nullptr, 128, 1.0f / SEQ);

            gmm2<3, 256><<<dim3(2048 / 256, 2048 / 256, 1), 512, 0, stream>>>(
                attn, nullptr, 2048, 0, vT, nullptr, 2048, 0,
                y, 2048, 0, gate, 2048, 0,
                nullptr, 0, nullptr, 2048, 0.f);

            gmm2<4, 128><<<dim3(1024 / 128, 2048 / 256), 512, 0, stream>>>(
                y, nullptr, 2048, 0, WoTh, nullptr, 2048, 0,
                nullptr, 0, 0, nullptr, 0, 0,
                out + (size_t)b * 2048 * 1024, 1024, b_out, 2048, 0.f);
        }
    }
}